// Round 1
// baseline (3056.807 us; speedup 1.0000x reference)
//
#include <hip/hip_runtime.h>
#include <math.h>

#define BB 32
#define PP 32
#define NN 4096
#define DD 768
#define MM 4096
#define KCH 8        // partial chunks per (b,p) in update
#define CHROWS 512   // rows per chunk (8*512 = 4096 covers worst case)
#define NT 128       // n-tile in sim gemm
#define KC 32        // k-chunk in sim gemm

__device__ __forceinline__ float wsum(float v) {
    for (int o = 32; o > 0; o >>= 1) v += __shfl_down(v, o, 64);
    return v;
}
__device__ __forceinline__ float wmax(float v) {
    for (int o = 32; o > 0; o >>= 1) v = fmaxf(v, __shfl_down(v, o, 64));
    return v;
}

// ---- tt = TEMP*TAU0 init -------------------------------------------------
__global__ void kinit(float* tt) {
    int i = blockIdx.x * 256 + threadIdx.x;
    if (i < BB * PP) tt[i] = 0.1f * 0.1f;
}

// ---- row L2 norms (feats rows / feats_org rows) --------------------------
__global__ void knorm_rows(const float* __restrict__ x, float* __restrict__ nrm, int rows) {
    int g = blockIdx.x * blockDim.x + threadIdx.x;
    int wid = g >> 6, lane = g & 63;
    if (wid >= rows) return;
    const float4* r = (const float4*)(x + (size_t)wid * DD);
    float s = 0.f;
#pragma unroll
    for (int q = 0; q < 3; ++q) {
        float4 v = r[lane + 64 * q];
        s += v.x * v.x + v.y * v.y + v.z * v.z + v.w * v.w;
    }
    s = wsum(s);
    if (lane == 0) nrm[wid] = sqrtf(s);
}

// ---- copy input prototypes to ws + norms ---------------------------------
__global__ __launch_bounds__(256) void kprotcopy(const float* __restrict__ src,
                                                 float* __restrict__ prot,
                                                 float* __restrict__ npn) {
    int bp = blockIdx.x;
    int t = threadIdx.x;
    __shared__ float red[4];
    const float* s = src + (size_t)bp * DD;
    float* d = prot + (size_t)bp * DD;
    float sq = 0.f;
#pragma unroll
    for (int r = 0; r < 3; ++r) {
        float v = s[t + 256 * r];
        d[t + 256 * r] = v;
        sq += v * v;
    }
    float m = wsum(sq);
    int lane = t & 63, w = t >> 6;
    if (!lane) red[w] = m;
    __syncthreads();
    if (t == 0) npn[bp] = sqrtf(red[0] + red[1] + red[2] + red[3]);
}

// ---- cosine-similarity GEMM:  out[b,p,n] = dot/max(npn*nfn,eps) ----------
__global__ __launch_bounds__(256) void ksim(
    const float* __restrict__ prot, const float* __restrict__ feats,
    const float* __restrict__ nfn, const float* __restrict__ npn,
    float* __restrict__ out, int ntiles, size_t fsb, int nsb, int Nout) {
    __shared__ float fsT[KC][NT + 2];  // [32][130] transposed feats tile
    __shared__ float psT[KC][PP + 4];  // [32][36]  transposed prot tile
    int bid = blockIdx.x;
    int b = bid / ntiles, nt = bid - b * ntiles;
    int n0 = nt * NT;
    const float4* f4 = (const float4*)(feats + (size_t)b * fsb + (size_t)n0 * DD);
    const float4* p4 = (const float4*)(prot + (size_t)b * (PP * DD));
    int tid = threadIdx.x;
    int tn = tid & 31, tp = tid >> 5;
    float acc[4][4] = {};
    float4 fA[4], pA;
#pragma unroll
    for (int q = 0; q < 4; ++q) {
        int i = q * 256 + tid;
        fA[q] = f4[(size_t)(i >> 3) * 192 + (i & 7)];
    }
    pA = p4[(size_t)(tid >> 3) * 192 + (tid & 7)];
    for (int kc = 0; kc < DD / KC; ++kc) {
        __syncthreads();
#pragma unroll
        for (int q = 0; q < 4; ++q) {
            int i = q * 256 + tid;
            int n_ = i >> 3, g = (i & 7) * 4;
            fsT[g + 0][n_] = fA[q].x;
            fsT[g + 1][n_] = fA[q].y;
            fsT[g + 2][n_] = fA[q].z;
            fsT[g + 3][n_] = fA[q].w;
        }
        {
            int p_ = tid >> 3, g = (tid & 7) * 4;
            psT[g + 0][p_] = pA.x;
            psT[g + 1][p_] = pA.y;
            psT[g + 2][p_] = pA.z;
            psT[g + 3][p_] = pA.w;
        }
        __syncthreads();
        if (kc + 1 < DD / KC) {
            int k8 = (kc + 1) * 8;
#pragma unroll
            for (int q = 0; q < 4; ++q) {
                int i = q * 256 + tid;
                fA[q] = f4[(size_t)(i >> 3) * 192 + k8 + (i & 7)];
            }
            pA = p4[(size_t)(tid >> 3) * 192 + k8 + (tid & 7)];
        }
#pragma unroll
        for (int k = 0; k < KC; ++k) {
            float2 na = *(const float2*)&fsT[k][2 * tn];
            float2 nb = *(const float2*)&fsT[k][2 * tn + 64];
            float4 pv = *(const float4*)&psT[k][4 * tp];
            acc[0][0] = fmaf(pv.x, na.x, acc[0][0]);
            acc[0][1] = fmaf(pv.x, na.y, acc[0][1]);
            acc[0][2] = fmaf(pv.x, nb.x, acc[0][2]);
            acc[0][3] = fmaf(pv.x, nb.y, acc[0][3]);
            acc[1][0] = fmaf(pv.y, na.x, acc[1][0]);
            acc[1][1] = fmaf(pv.y, na.y, acc[1][1]);
            acc[1][2] = fmaf(pv.y, nb.x, acc[1][2]);
            acc[1][3] = fmaf(pv.y, nb.y, acc[1][3]);
            acc[2][0] = fmaf(pv.z, na.x, acc[2][0]);
            acc[2][1] = fmaf(pv.z, na.y, acc[2][1]);
            acc[2][2] = fmaf(pv.z, nb.x, acc[2][2]);
            acc[2][3] = fmaf(pv.z, nb.y, acc[2][3]);
            acc[3][0] = fmaf(pv.w, na.x, acc[3][0]);
            acc[3][1] = fmaf(pv.w, na.y, acc[3][1]);
            acc[3][2] = fmaf(pv.w, nb.x, acc[3][2]);
            acc[3][3] = fmaf(pv.w, nb.y, acc[3][3]);
        }
    }
    int nj[4] = {2 * tn, 2 * tn + 1, 2 * tn + 64, 2 * tn + 65};
    float nf[4];
#pragma unroll
    for (int j = 0; j < 4; ++j) nf[j] = nfn[(size_t)b * nsb + n0 + nj[j]];
#pragma unroll
    for (int i = 0; i < 4; ++i) {
        int p = 4 * tp + i;
        float pn = npn[b * PP + p];
        float* ob = out + (size_t)(b * PP + p) * Nout + n0;
#pragma unroll
        for (int j = 0; j < 4; ++j) ob[nj[j]] = acc[i][j] / fmaxf(pn * nf[j], 1e-8f);
    }
}

// ---- density -> tau (uses previous iter's lists, this iter's sim) --------
__global__ void kdens(const float* __restrict__ sim, const int* __restrict__ nlist,
                      const int* __restrict__ offs, const int* __restrict__ cnt,
                      float* __restrict__ tt) {
    int g = blockIdx.x * blockDim.x + threadIdx.x;
    int wid = g >> 6, lane = g & 63;
    if (wid >= BB * PP) return;
    int b = wid >> 5;
    int c = cnt[wid];
    const float* sp = sim + (size_t)wid * NN;
    const int* lp = nlist + b * NN + offs[wid];
    float s = 0.f;
    for (int j = lane; j < c; j += 64) s += sp[lp[j]];
    s = wsum(s);
    if (lane == 0) {
        float density = 1.0f;
        if (c >= 1) density = 1.0f - s / (float)c;
        float tau = fmaxf(density, 1e-10f);
        tt[wid] = 0.1f * tau;
    }
}

// ---- per-row softmax stats: xmax = max(sim)/tt, Z = sum exp(x - xmax) ----
__global__ __launch_bounds__(256) void krowstats(const float* __restrict__ sim,
                                                 const float* __restrict__ tt,
                                                 float* __restrict__ xmax,
                                                 float* __restrict__ Zr) {
    int bp = blockIdx.x;
    int t = threadIdx.x;
    const float4* r4 = (const float4*)(sim + (size_t)bp * NN);
    float v[16];
    float mx = -3.4e38f;
#pragma unroll
    for (int q = 0; q < 4; ++q) {
        float4 x = r4[t + 256 * q];
        v[4 * q + 0] = x.x; v[4 * q + 1] = x.y; v[4 * q + 2] = x.z; v[4 * q + 3] = x.w;
        mx = fmaxf(mx, fmaxf(fmaxf(x.x, x.y), fmaxf(x.z, x.w)));
    }
    __shared__ float red[4];
    float m = wmax(mx);
    int lane = t & 63, w = t >> 6;
    if (!lane) red[w] = m;
    __syncthreads();
    float bm = fmaxf(fmaxf(red[0], red[1]), fmaxf(red[2], red[3]));
    float ttv = tt[bp];
    float xm = bm / ttv;
    float s = 0.f;
#pragma unroll
    for (int i = 0; i < 16; ++i) s += expf(v[i] / ttv - xm);
    __syncthreads();
    float sm = wsum(s);
    if (!lane) red[w] = sm;
    __syncthreads();
    if (t == 0) {
        xmax[bp] = xm;
        Zr[bp] = red[0] + red[1] + red[2] + red[3];
    }
}

__global__ void kzero(int* cnt) {
    int i = blockIdx.x * 256 + threadIdx.x;
    if (i < BB * PP) cnt[i] = 0;
}

// ---- per-(b,n): argmax_p weight, store idx & selected weight -------------
__global__ __launch_bounds__(256) void kargmax(const float* __restrict__ sim,
                                               const float* __restrict__ tt,
                                               const float* __restrict__ xmax,
                                               const float* __restrict__ Zr,
                                               float* __restrict__ wsel,
                                               int* __restrict__ idx,
                                               int* __restrict__ cnt) {
    int gi = blockIdx.x * 256 + threadIdx.x;
    int b = gi >> 12;
    int n = gi & (NN - 1);
    const float* sp = sim + (size_t)b * PP * NN + n;
    float best = -1.0f;
    int bi = 0;
    for (int p = 0; p < PP; ++p) {
        float s = sp[(size_t)p * NN];
        float w = expf(s / tt[b * PP + p] - xmax[b * PP + p]) / Zr[b * PP + p];
        if (w > best) { best = w; bi = p; }
    }
    idx[gi] = bi;
    wsel[gi] = best;
    atomicAdd(&cnt[b * PP + bi], 1);
}

// ---- exclusive prefix over p per b ---------------------------------------
__global__ void koffsets(const int* __restrict__ cnt, int* __restrict__ offs) {
    int b = threadIdx.x;
    if (b >= BB) return;
    int s = 0;
    for (int p = 0; p < PP; ++p) {
        offs[b * PP + p] = s;
        s += cnt[b * PP + p];
    }
}

// ---- deterministic bucket lists (one wave per (b,p), ballot ranks) -------
__global__ void klist(const int* __restrict__ idx, const int* __restrict__ offs,
                      int* __restrict__ nlist) {
    int g = blockIdx.x * blockDim.x + threadIdx.x;
    int wid = g >> 6, lane = g & 63;
    if (wid >= BB * PP) return;
    int b = wid >> 5, p = wid & 31;
    const int* ib = idx + b * NN;
    int base = offs[wid];
    for (int s = 0; s < NN; s += 64) {
        int v = ib[s + lane];
        bool m = (v == p);
        unsigned long long bal = __ballot(m);
        if (m) {
            int rank = __popcll(bal & ((1ull << lane) - 1ull));
            nlist[b * NN + base + rank] = s + lane;
        }
        base += __popcll(bal);
    }
}

// ---- prototype update partials: sum_{n in bucket chunk} w * f[n,:] -------
__global__ __launch_bounds__(256) void kupdate(const float* __restrict__ feats,
                                               const float* __restrict__ wsel,
                                               const int* __restrict__ nlist,
                                               const int* __restrict__ offs,
                                               const int* __restrict__ cnt,
                                               float* __restrict__ part) {
    int bid = blockIdx.x;
    int k = bid & (KCH - 1);
    int bp = bid >> 3;
    int b = bp >> 5;
    int t = threadIdx.x;
    int c = cnt[bp];
    int j0 = k * CHROWS;
    int j1 = min(c, j0 + CHROWS);
    float a0 = 0.f, a1 = 0.f, a2 = 0.f;
    if (j0 < j1) {
        const int* lp = nlist + b * NN + offs[bp];
        const float* fb = feats + (size_t)b * NN * DD;
        int n_next = lp[j0];
        float w_next = wsel[b * NN + n_next];
        for (int j = j0; j < j1; ++j) {
            int n = n_next;
            float wv = w_next;
            if (j + 1 < j1) {
                n_next = lp[j + 1];
                w_next = wsel[b * NN + n_next];
            }
            const float* fr = fb + (size_t)n * DD + t;
            a0 = fmaf(wv, fr[0], a0);
            a1 = fmaf(wv, fr[256], a1);
            a2 = fmaf(wv, fr[512], a2);
        }
    }
    float* pr = part + ((size_t)bp * KCH + k) * DD + t;
    pr[0] = a0;
    pr[256] = a1;
    pr[512] = a2;
}

// ---- reduce partials -> prototypes (+norms, + optional d_out write) ------
__global__ __launch_bounds__(256) void kreduce(const float* __restrict__ part,
                                               float* __restrict__ prot,
                                               float* __restrict__ npn,
                                               float* __restrict__ outp) {
    int bp = blockIdx.x;
    int t = threadIdx.x;
    __shared__ float red[4];
    float sq = 0.f;
#pragma unroll
    for (int r = 0; r < 3; ++r) {
        int d = t + 256 * r;
        float s = 0.f;
#pragma unroll
        for (int kk = 0; kk < KCH; ++kk) s += part[((size_t)bp * KCH + kk) * DD + d];
        prot[(size_t)bp * DD + d] = s;
        if (outp) outp[(size_t)bp * DD + d] = s;
        sq += s * s;
    }
    float m = wsum(sq);
    int lane = t & 63, w = t >> 6;
    if (!lane) red[w] = m;
    __syncthreads();
    if (t == 0) npn[bp] = sqrtf(red[0] + red[1] + red[2] + red[3]);
}

extern "C" void kernel_launch(void* const* d_in, const int* in_sizes, int n_in,
                              void* d_out, int out_size, void* d_ws, size_t ws_size,
                              hipStream_t stream) {
    const float* protIn = (const float*)d_in[0];
    const float* feats = (const float*)d_in[1];
    const float* forg = (const float*)d_in[2];
    float* out = (float*)d_out;

    char* w = (char*)d_ws;
    auto alloc = [&](size_t bytes) {
        char* p = w;
        w += (bytes + 255) & ~(size_t)255;
        return p;
    };
    float* sim = (float*)alloc((size_t)BB * PP * NN * 4);
    float* prot = (float*)alloc((size_t)BB * PP * DD * 4);
    float* part = (float*)alloc((size_t)BB * PP * KCH * DD * 4);
    float* nfn = (float*)alloc((size_t)BB * NN * 4);
    float* norg = (float*)alloc((size_t)MM * 4);
    float* npn = (float*)alloc(BB * PP * 4);
    float* xmax = (float*)alloc(BB * PP * 4);
    float* Zr = (float*)alloc(BB * PP * 4);
    float* tt = (float*)alloc(BB * PP * 4);
    float* wselp = (float*)alloc((size_t)BB * NN * 4);
    int* idx = (int*)alloc((size_t)BB * NN * 4);
    int* nlist = (int*)alloc((size_t)BB * NN * 4);
    int* cnt = (int*)alloc(BB * PP * 4);
    int* offs = (int*)alloc(BB * PP * 4);

    kinit<<<4, 256, 0, stream>>>(tt);
    kprotcopy<<<BB * PP, 256, 0, stream>>>(protIn, prot, npn);
    knorm_rows<<<(BB * NN) / 4, 256, 0, stream>>>(feats, nfn, BB * NN);
    knorm_rows<<<MM / 4, 256, 0, stream>>>(forg, norg, MM);

    for (int t = 0; t < 5; ++t) {
        ksim<<<BB * (NN / NT), 256, 0, stream>>>(prot, feats, nfn, npn, sim, NN / NT,
                                                 (size_t)NN * DD, NN, NN);
        if (t > 0) kdens<<<(BB * PP) / 4, 256, 0, stream>>>(sim, nlist, offs, cnt, tt);
        krowstats<<<BB * PP, 256, 0, stream>>>(sim, tt, xmax, Zr);
        kzero<<<4, 256, 0, stream>>>(cnt);
        kargmax<<<(BB * NN) / 256, 256, 0, stream>>>(sim, tt, xmax, Zr, wselp, idx, cnt);
        koffsets<<<1, 64, 0, stream>>>(cnt, offs);
        klist<<<(BB * PP) / 4, 256, 0, stream>>>(idx, offs, nlist);
        kupdate<<<BB * PP * KCH, 256, 0, stream>>>(feats, wselp, nlist, offs, cnt, part);
        kreduce<<<BB * PP, 256, 0, stream>>>(part, prot, npn, (t == 4) ? out : nullptr);
    }
    // final similarity against feats_org -> second output region
    ksim<<<BB * (MM / NT), 256, 0, stream>>>(prot, forg, norg, npn,
                                             out + (size_t)BB * PP * DD, MM / NT,
                                             (size_t)0, 0, MM);
}

// Round 2
// 2393.455 us; speedup vs baseline: 1.2772x; 1.2772x over previous
//
#include <hip/hip_runtime.h>
#include <math.h>

#define BB 32
#define PP 32
#define NN 4096
#define DD 768
#define MM 4096
#define NSP 8        // n splits in update
#define DCH 256      // d chunk in update
#define NPER (NN / NSP)
#define NT 128       // n-tile in sim gemm
#define KC 32        // k-chunk in sim gemm

__device__ __forceinline__ float wsum(float v) {
    for (int o = 32; o > 0; o >>= 1) v += __shfl_down(v, o, 64);
    return v;
}
__device__ __forceinline__ float wmax(float v) {
    for (int o = 32; o > 0; o >>= 1) v = fmaxf(v, __shfl_down(v, o, 64));
    return v;
}

// ---- tt = TEMP*TAU0 init -------------------------------------------------
__global__ void kinit(float* tt) {
    int i = blockIdx.x * 256 + threadIdx.x;
    if (i < BB * PP) tt[i] = 0.1f * 0.1f;
}

// ---- row L2 norms (feats rows / feats_org rows) --------------------------
__global__ void knorm_rows(const float* __restrict__ x, float* __restrict__ nrm, int rows) {
    int g = blockIdx.x * blockDim.x + threadIdx.x;
    int wid = g >> 6, lane = g & 63;
    if (wid >= rows) return;
    const float4* r = (const float4*)(x + (size_t)wid * DD);
    float s = 0.f;
#pragma unroll
    for (int q = 0; q < 3; ++q) {
        float4 v = r[lane + 64 * q];
        s += v.x * v.x + v.y * v.y + v.z * v.z + v.w * v.w;
    }
    s = wsum(s);
    if (lane == 0) nrm[wid] = sqrtf(s);
}

// ---- copy input prototypes to ws + norms ---------------------------------
__global__ __launch_bounds__(256) void kprotcopy(const float* __restrict__ src,
                                                 float* __restrict__ prot,
                                                 float* __restrict__ npn) {
    int bp = blockIdx.x;
    int t = threadIdx.x;
    __shared__ float red[4];
    const float* s = src + (size_t)bp * DD;
    float* d = prot + (size_t)bp * DD;
    float sq = 0.f;
#pragma unroll
    for (int r = 0; r < 3; ++r) {
        float v = s[t + 256 * r];
        d[t + 256 * r] = v;
        sq += v * v;
    }
    float m = wsum(sq);
    int lane = t & 63, w = t >> 6;
    if (!lane) red[w] = m;
    __syncthreads();
    if (t == 0) npn[bp] = sqrtf(red[0] + red[1] + red[2] + red[3]);
}

// ---- cosine-similarity GEMM:  out[b,p,n] = dot/max(npn*nfn,eps) ----------
__global__ __launch_bounds__(256) void ksim(
    const float* __restrict__ prot, const float* __restrict__ feats,
    const float* __restrict__ nfn, const float* __restrict__ npn,
    float* __restrict__ out, int ntiles, size_t fsb, int nsb, int Nout) {
    __shared__ float fsT[KC][NT + 2];  // [32][130] transposed feats tile
    __shared__ float psT[KC][PP + 4];  // [32][36]  transposed prot tile
    int bid = blockIdx.x;
    int b = bid / ntiles, nt = bid - b * ntiles;
    int n0 = nt * NT;
    const float4* f4 = (const float4*)(feats + (size_t)b * fsb + (size_t)n0 * DD);
    const float4* p4 = (const float4*)(prot + (size_t)b * (PP * DD));
    int tid = threadIdx.x;
    int tn = tid & 31, tp = tid >> 5;
    float acc[4][4] = {};
    float4 fA[4], pA;
#pragma unroll
    for (int q = 0; q < 4; ++q) {
        int i = q * 256 + tid;
        fA[q] = f4[(size_t)(i >> 3) * 192 + (i & 7)];
    }
    pA = p4[(size_t)(tid >> 3) * 192 + (tid & 7)];
    for (int kc = 0; kc < DD / KC; ++kc) {
        __syncthreads();
#pragma unroll
        for (int q = 0; q < 4; ++q) {
            int i = q * 256 + tid;
            int n_ = i >> 3, g = (i & 7) * 4;
            fsT[g + 0][n_] = fA[q].x;
            fsT[g + 1][n_] = fA[q].y;
            fsT[g + 2][n_] = fA[q].z;
            fsT[g + 3][n_] = fA[q].w;
        }
        {
            int p_ = tid >> 3, g = (tid & 7) * 4;
            psT[g + 0][p_] = pA.x;
            psT[g + 1][p_] = pA.y;
            psT[g + 2][p_] = pA.z;
            psT[g + 3][p_] = pA.w;
        }
        __syncthreads();
        if (kc + 1 < DD / KC) {
            int k8 = (kc + 1) * 8;
#pragma unroll
            for (int q = 0; q < 4; ++q) {
                int i = q * 256 + tid;
                fA[q] = f4[(size_t)(i >> 3) * 192 + k8 + (i & 7)];
            }
            pA = p4[(size_t)(tid >> 3) * 192 + k8 + (tid & 7)];
        }
#pragma unroll
        for (int k = 0; k < KC; ++k) {
            float2 na = *(const float2*)&fsT[k][2 * tn];
            float2 nb = *(const float2*)&fsT[k][2 * tn + 64];
            float4 pv = *(const float4*)&psT[k][4 * tp];
            acc[0][0] = fmaf(pv.x, na.x, acc[0][0]);
            acc[0][1] = fmaf(pv.x, na.y, acc[0][1]);
            acc[0][2] = fmaf(pv.x, nb.x, acc[0][2]);
            acc[0][3] = fmaf(pv.x, nb.y, acc[0][3]);
            acc[1][0] = fmaf(pv.y, na.x, acc[1][0]);
            acc[1][1] = fmaf(pv.y, na.y, acc[1][1]);
            acc[1][2] = fmaf(pv.y, nb.x, acc[1][2]);
            acc[1][3] = fmaf(pv.y, nb.y, acc[1][3]);
            acc[2][0] = fmaf(pv.z, na.x, acc[2][0]);
            acc[2][1] = fmaf(pv.z, na.y, acc[2][1]);
            acc[2][2] = fmaf(pv.z, nb.x, acc[2][2]);
            acc[2][3] = fmaf(pv.z, nb.y, acc[2][3]);
            acc[3][0] = fmaf(pv.w, na.x, acc[3][0]);
            acc[3][1] = fmaf(pv.w, na.y, acc[3][1]);
            acc[3][2] = fmaf(pv.w, nb.x, acc[3][2]);
            acc[3][3] = fmaf(pv.w, nb.y, acc[3][3]);
        }
    }
    int nj[4] = {2 * tn, 2 * tn + 1, 2 * tn + 64, 2 * tn + 65};
    float nf[4];
#pragma unroll
    for (int j = 0; j < 4; ++j) nf[j] = nfn[(size_t)b * nsb + n0 + nj[j]];
#pragma unroll
    for (int i = 0; i < 4; ++i) {
        int p = 4 * tp + i;
        float pn = npn[b * PP + p];
        float* ob = out + (size_t)(b * PP + p) * Nout + n0;
#pragma unroll
        for (int j = 0; j < 4; ++j) ob[nj[j]] = acc[i][j] / fmaxf(pn * nf[j], 1e-8f);
    }
}

// ---- density -> tau (uses previous iter's idx/cnt, this iter's sim) ------
__global__ void kdens(const float* __restrict__ sim, const int* __restrict__ idxv,
                      const int* __restrict__ cnt, float* __restrict__ tt) {
    int g = blockIdx.x * blockDim.x + threadIdx.x;
    int wid = g >> 6, lane = g & 63;
    if (wid >= BB * PP) return;
    int b = wid >> 5, p = wid & 31;
    int c = cnt[wid];
    const float* sp = sim + (size_t)wid * NN;
    const int* ib = idxv + b * NN;
    float s = 0.f;
    for (int j = lane; j < NN; j += 64)
        if (ib[j] == p) s += sp[j];
    s = wsum(s);
    if (lane == 0) {
        float density = 1.0f;
        if (c >= 1) density = 1.0f - s / (float)c;
        float tau = fmaxf(density, 1e-10f);
        tt[wid] = 0.1f * tau;
    }
}

// ---- per-row softmax stats: xmax = max(sim)/tt, Z = sum exp(x - xmax) ----
__global__ __launch_bounds__(256) void krowstats(const float* __restrict__ sim,
                                                 const float* __restrict__ tt,
                                                 float* __restrict__ xmax,
                                                 float* __restrict__ Zr) {
    int bp = blockIdx.x;
    int t = threadIdx.x;
    const float4* r4 = (const float4*)(sim + (size_t)bp * NN);
    float v[16];
    float mx = -3.4e38f;
#pragma unroll
    for (int q = 0; q < 4; ++q) {
        float4 x = r4[t + 256 * q];
        v[4 * q + 0] = x.x; v[4 * q + 1] = x.y; v[4 * q + 2] = x.z; v[4 * q + 3] = x.w;
        mx = fmaxf(mx, fmaxf(fmaxf(x.x, x.y), fmaxf(x.z, x.w)));
    }
    __shared__ float red[4];
    float m = wmax(mx);
    int lane = t & 63, w = t >> 6;
    if (!lane) red[w] = m;
    __syncthreads();
    float bm = fmaxf(fmaxf(red[0], red[1]), fmaxf(red[2], red[3]));
    float ttv = tt[bp];
    float xm = bm / ttv;
    float s = 0.f;
#pragma unroll
    for (int i = 0; i < 16; ++i) s += expf(v[i] / ttv - xm);
    __syncthreads();
    float sm = wsum(s);
    if (!lane) red[w] = sm;
    __syncthreads();
    if (t == 0) {
        xmax[bp] = xm;
        Zr[bp] = red[0] + red[1] + red[2] + red[3];
    }
}

__global__ void kzero(int* cnt) {
    int i = blockIdx.x * 256 + threadIdx.x;
    if (i < BB * PP) cnt[i] = 0;
}

// ---- per-(b,n): argmax_p weight, store idx & selected weight -------------
__global__ __launch_bounds__(256) void kargmax(const float* __restrict__ sim,
                                               const float* __restrict__ tt,
                                               const float* __restrict__ xmax,
                                               const float* __restrict__ Zr,
                                               float* __restrict__ wsel,
                                               int* __restrict__ idxv,
                                               int* __restrict__ cnt) {
    int gi = blockIdx.x * 256 + threadIdx.x;
    int b = gi >> 12;
    int n = gi & (NN - 1);
    const float* sp = sim + (size_t)b * PP * NN + n;
    float best = -1.0f;
    int bi = 0;
    for (int p = 0; p < PP; ++p) {
        float s = sp[(size_t)p * NN];
        float w = expf(s / tt[b * PP + p] - xmax[b * PP + p]) / Zr[b * PP + p];
        if (w > best) { best = w; bi = p; }
    }
    idxv[gi] = bi;
    wsel[gi] = best;
    atomicAdd(&cnt[b * PP + bi], 1);
}

// ---- prototype update partials: dense scan, column-private LDS scatter ---
// grid: b(32) x dc(3) x ns(NSP); block 256 threads; thread t owns LDS col t.
__global__ __launch_bounds__(256) void kupdate(const float* __restrict__ feats,
                                               const float* __restrict__ wsel,
                                               const int* __restrict__ idxv,
                                               float* __restrict__ part) {
    __shared__ float acc[PP][DCH];
    int bid = blockIdx.x;
    int ns = bid & (NSP - 1);
    int dc = (bid >> 3) % 3;
    int b = bid / (3 * NSP);
    int t = threadIdx.x;
#pragma unroll
    for (int p = 0; p < PP; ++p) acc[p][t] = 0.f;
    int n0 = ns * NPER;
    const int* ib = idxv + b * NN + n0;
    const float* wb = wsel + b * NN + n0;
    const float* fb = feats + ((size_t)b * NN + n0) * DD + dc * DCH + t;
    // register-cache the running sum for the current (block-uniform) bucket p;
    // flush to LDS only when p changes -> no dependent LDS RMW chain.
    int curp = ib[0];
    float racc = 0.f;
#pragma unroll 4
    for (int j = 0; j < NPER; ++j) {
        int p = ib[j];
        float w = wb[j];
        float f = fb[(size_t)j * DD];
        if (p != curp) {            // block-uniform branch, no divergence
            acc[curp][t] += racc;
            racc = 0.f;
            curp = p;
        }
        racc = fmaf(w, f, racc);
    }
    acc[curp][t] += racc;
    float* pr = part + (((size_t)b * NSP + ns) * PP) * DD + dc * DCH + t;
#pragma unroll
    for (int p = 0; p < PP; ++p) pr[(size_t)p * DD] = acc[p][t];
}

// ---- reduce partials -> prototypes (+norms, + optional d_out write) ------
__global__ __launch_bounds__(256) void kreduce(const float* __restrict__ part,
                                               float* __restrict__ prot,
                                               float* __restrict__ npn,
                                               float* __restrict__ outp) {
    int bp = blockIdx.x;
    int b = bp >> 5, p = bp & 31;
    int t = threadIdx.x;
    __shared__ float red[4];
    float sq = 0.f;
#pragma unroll
    for (int r = 0; r < 3; ++r) {
        int d = t + 256 * r;
        float s = 0.f;
#pragma unroll
        for (int ns = 0; ns < NSP; ++ns)
            s += part[(((size_t)b * NSP + ns) * PP + p) * DD + d];
        prot[(size_t)bp * DD + d] = s;
        if (outp) outp[(size_t)bp * DD + d] = s;
        sq += s * s;
    }
    float m = wsum(sq);
    int lane = t & 63, w = t >> 6;
    if (!lane) red[w] = m;
    __syncthreads();
    if (t == 0) npn[bp] = sqrtf(red[0] + red[1] + red[2] + red[3]);
}

extern "C" void kernel_launch(void* const* d_in, const int* in_sizes, int n_in,
                              void* d_out, int out_size, void* d_ws, size_t ws_size,
                              hipStream_t stream) {
    const float* protIn = (const float*)d_in[0];
    const float* feats = (const float*)d_in[1];
    const float* forg = (const float*)d_in[2];
    float* out = (float*)d_out;

    char* w = (char*)d_ws;
    auto alloc = [&](size_t bytes) {
        char* p = w;
        w += (bytes + 255) & ~(size_t)255;
        return p;
    };
    float* sim = (float*)alloc((size_t)BB * PP * NN * 4);
    float* prot = (float*)alloc((size_t)BB * PP * DD * 4);
    float* part = (float*)alloc((size_t)BB * NSP * PP * DD * 4);
    float* nfn = (float*)alloc((size_t)BB * NN * 4);
    float* norg = (float*)alloc((size_t)MM * 4);
    float* npn = (float*)alloc(BB * PP * 4);
    float* xmax = (float*)alloc(BB * PP * 4);
    float* Zr = (float*)alloc(BB * PP * 4);
    float* tt = (float*)alloc(BB * PP * 4);
    float* wselp = (float*)alloc((size_t)BB * NN * 4);
    int* idx = (int*)alloc((size_t)BB * NN * 4);
    int* cnt = (int*)alloc(BB * PP * 4);

    kinit<<<4, 256, 0, stream>>>(tt);
    kprotcopy<<<BB * PP, 256, 0, stream>>>(protIn, prot, npn);
    knorm_rows<<<(BB * NN) / 4, 256, 0, stream>>>(feats, nfn, BB * NN);
    knorm_rows<<<MM / 4, 256, 0, stream>>>(forg, norg, MM);

    for (int t = 0; t < 5; ++t) {
        ksim<<<BB * (NN / NT), 256, 0, stream>>>(prot, feats, nfn, npn, sim, NN / NT,
                                                 (size_t)NN * DD, NN, NN);
        if (t > 0) kdens<<<(BB * PP) / 4, 256, 0, stream>>>(sim, idx, cnt, tt);
        krowstats<<<BB * PP, 256, 0, stream>>>(sim, tt, xmax, Zr);
        kzero<<<4, 256, 0, stream>>>(cnt);
        kargmax<<<(BB * NN) / 256, 256, 0, stream>>>(sim, tt, xmax, Zr, wselp, idx, cnt);
        kupdate<<<BB * 3 * NSP, 256, 0, stream>>>(feats, wselp, idx, part);
        kreduce<<<BB * PP, 256, 0, stream>>>(part, prot, npn, (t == 4) ? out : nullptr);
    }
    // final similarity against feats_org -> second output region
    ksim<<<BB * (MM / NT), 256, 0, stream>>>(prot, forg, norg, npn,
                                             out + (size_t)BB * PP * DD, MM / NT,
                                             (size_t)0, 0, MM);
}

// Round 3
// 1736.214 us; speedup vs baseline: 1.7606x; 1.3785x over previous
//
#include <hip/hip_runtime.h>
#include <math.h>

#define BB 32
#define PP 32
#define NN 4096
#define DD 768
#define MM 4096
#define WROWS 128          // rows per update window
#define NWIN (NN / WROWS)  // 32 windows per b
#define NT 128             // n-tile in sim gemm
#define KC 32              // k-chunk in sim gemm

__device__ __forceinline__ float wsum(float v) {
    for (int o = 32; o > 0; o >>= 1) v += __shfl_down(v, o, 64);
    return v;
}
__device__ __forceinline__ float wmax(float v) {
    for (int o = 32; o > 0; o >>= 1) v = fmaxf(v, __shfl_down(v, o, 64));
    return v;
}

// ---- tt = TEMP*TAU0 init -------------------------------------------------
__global__ void kinit(float* tt) {
    int i = blockIdx.x * 256 + threadIdx.x;
    if (i < BB * PP) tt[i] = 0.1f * 0.1f;
}

// ---- row L2 norms (feats rows / feats_org rows) --------------------------
__global__ void knorm_rows(const float* __restrict__ x, float* __restrict__ nrm, int rows) {
    int g = blockIdx.x * blockDim.x + threadIdx.x;
    int wid = g >> 6, lane = g & 63;
    if (wid >= rows) return;
    const float4* r = (const float4*)(x + (size_t)wid * DD);
    float s = 0.f;
#pragma unroll
    for (int q = 0; q < 3; ++q) {
        float4 v = r[lane + 64 * q];
        s += v.x * v.x + v.y * v.y + v.z * v.z + v.w * v.w;
    }
    s = wsum(s);
    if (lane == 0) nrm[wid] = sqrtf(s);
}

// ---- copy input prototypes to ws + norms ---------------------------------
__global__ __launch_bounds__(256) void kprotcopy(const float* __restrict__ src,
                                                 float* __restrict__ prot,
                                                 float* __restrict__ npn) {
    int bp = blockIdx.x;
    int t = threadIdx.x;
    __shared__ float red[4];
    const float* s = src + (size_t)bp * DD;
    float* d = prot + (size_t)bp * DD;
    float sq = 0.f;
#pragma unroll
    for (int r = 0; r < 3; ++r) {
        float v = s[t + 256 * r];
        d[t + 256 * r] = v;
        sq += v * v;
    }
    float m = wsum(sq);
    int lane = t & 63, w = t >> 6;
    if (!lane) red[w] = m;
    __syncthreads();
    if (t == 0) npn[bp] = sqrtf(red[0] + red[1] + red[2] + red[3]);
}

// ---- cosine-similarity GEMM:  out[b,p,n] = dot/max(npn*nfn,eps) ----------
__global__ __launch_bounds__(256) void ksim(
    const float* __restrict__ prot, const float* __restrict__ feats,
    const float* __restrict__ nfn, const float* __restrict__ npn,
    float* __restrict__ out, int ntiles, size_t fsb, int nsb, int Nout) {
    __shared__ float fsT[KC][NT + 2];  // [32][130] transposed feats tile
    __shared__ float psT[KC][PP + 4];  // [32][36]  transposed prot tile
    int bid = blockIdx.x;
    int b = bid / ntiles, nt = bid - b * ntiles;
    int n0 = nt * NT;
    const float4* f4 = (const float4*)(feats + (size_t)b * fsb + (size_t)n0 * DD);
    const float4* p4 = (const float4*)(prot + (size_t)b * (PP * DD));
    int tid = threadIdx.x;
    int tn = tid & 31, tp = tid >> 5;
    float acc[4][4] = {};
    float4 fA[4], pA;
#pragma unroll
    for (int q = 0; q < 4; ++q) {
        int i = q * 256 + tid;
        fA[q] = f4[(size_t)(i >> 3) * 192 + (i & 7)];
    }
    pA = p4[(size_t)(tid >> 3) * 192 + (tid & 7)];
    for (int kc = 0; kc < DD / KC; ++kc) {
        __syncthreads();
#pragma unroll
        for (int q = 0; q < 4; ++q) {
            int i = q * 256 + tid;
            int n_ = i >> 3, g = (i & 7) * 4;
            fsT[g + 0][n_] = fA[q].x;
            fsT[g + 1][n_] = fA[q].y;
            fsT[g + 2][n_] = fA[q].z;
            fsT[g + 3][n_] = fA[q].w;
        }
        {
            int p_ = tid >> 3, g = (tid & 7) * 4;
            psT[g + 0][p_] = pA.x;
            psT[g + 1][p_] = pA.y;
            psT[g + 2][p_] = pA.z;
            psT[g + 3][p_] = pA.w;
        }
        __syncthreads();
        if (kc + 1 < DD / KC) {
            int k8 = (kc + 1) * 8;
#pragma unroll
            for (int q = 0; q < 4; ++q) {
                int i = q * 256 + tid;
                fA[q] = f4[(size_t)(i >> 3) * 192 + k8 + (i & 7)];
            }
            pA = p4[(size_t)(tid >> 3) * 192 + k8 + (tid & 7)];
        }
#pragma unroll
        for (int k = 0; k < KC; ++k) {
            float2 na = *(const float2*)&fsT[k][2 * tn];
            float2 nb = *(const float2*)&fsT[k][2 * tn + 64];
            float4 pv = *(const float4*)&psT[k][4 * tp];
            acc[0][0] = fmaf(pv.x, na.x, acc[0][0]);
            acc[0][1] = fmaf(pv.x, na.y, acc[0][1]);
            acc[0][2] = fmaf(pv.x, nb.x, acc[0][2]);
            acc[0][3] = fmaf(pv.x, nb.y, acc[0][3]);
            acc[1][0] = fmaf(pv.y, na.x, acc[1][0]);
            acc[1][1] = fmaf(pv.y, na.y, acc[1][1]);
            acc[1][2] = fmaf(pv.y, nb.x, acc[1][2]);
            acc[1][3] = fmaf(pv.y, nb.y, acc[1][3]);
            acc[2][0] = fmaf(pv.z, na.x, acc[2][0]);
            acc[2][1] = fmaf(pv.z, na.y, acc[2][1]);
            acc[2][2] = fmaf(pv.z, nb.x, acc[2][2]);
            acc[2][3] = fmaf(pv.z, nb.y, acc[2][3]);
            acc[3][0] = fmaf(pv.w, na.x, acc[3][0]);
            acc[3][1] = fmaf(pv.w, na.y, acc[3][1]);
            acc[3][2] = fmaf(pv.w, nb.x, acc[3][2]);
            acc[3][3] = fmaf(pv.w, nb.y, acc[3][3]);
        }
    }
    int nj[4] = {2 * tn, 2 * tn + 1, 2 * tn + 64, 2 * tn + 65};
    float nf[4];
#pragma unroll
    for (int j = 0; j < 4; ++j) nf[j] = nfn[(size_t)b * nsb + n0 + nj[j]];
#pragma unroll
    for (int i = 0; i < 4; ++i) {
        int p = 4 * tp + i;
        float pn = npn[b * PP + p];
        float* ob = out + (size_t)(b * PP + p) * Nout + n0;
#pragma unroll
        for (int j = 0; j < 4; ++j) ob[nj[j]] = acc[i][j] / fmaxf(pn * nf[j], 1e-8f);
    }
}

// ---- density -> tau (prev iter's sorted buckets, this iter's sim) --------
__global__ void kdens(const float* __restrict__ sim, const int* __restrict__ sortn,
                      const int* __restrict__ offs, const int* __restrict__ cnt,
                      float* __restrict__ tt) {
    int g = blockIdx.x * blockDim.x + threadIdx.x;
    int wid = g >> 6, lane = g & 63;
    if (wid >= BB * PP) return;
    int b = wid >> 5;
    int c = cnt[wid];
    const float* sp = sim + (size_t)wid * NN;
    const int* lp = sortn + b * NN + offs[wid];
    float s = 0.f;
    for (int j = lane; j < c; j += 64) s += sp[lp[j] & 0xFFF];
    s = wsum(s);
    if (lane == 0) {
        float density = 1.0f;
        if (c >= 1) density = 1.0f - s / (float)c;
        float tau = fmaxf(density, 1e-10f);
        tt[wid] = 0.1f * tau;
    }
}

// ---- per-row softmax stats: xmax = max(sim)/tt, Z = sum exp(x - xmax) ----
__global__ __launch_bounds__(256) void krowstats(const float* __restrict__ sim,
                                                 const float* __restrict__ tt,
                                                 float* __restrict__ xmax,
                                                 float* __restrict__ Zr) {
    int bp = blockIdx.x;
    int t = threadIdx.x;
    const float4* r4 = (const float4*)(sim + (size_t)bp * NN);
    float v[16];
    float mx = -3.4e38f;
#pragma unroll
    for (int q = 0; q < 4; ++q) {
        float4 x = r4[t + 256 * q];
        v[4 * q + 0] = x.x; v[4 * q + 1] = x.y; v[4 * q + 2] = x.z; v[4 * q + 3] = x.w;
        mx = fmaxf(mx, fmaxf(fmaxf(x.x, x.y), fmaxf(x.z, x.w)));
    }
    __shared__ float red[4];
    float m = wmax(mx);
    int lane = t & 63, w = t >> 6;
    if (!lane) red[w] = m;
    __syncthreads();
    float bm = fmaxf(fmaxf(red[0], red[1]), fmaxf(red[2], red[3]));
    float ttv = tt[bp];
    float xm = bm / ttv;
    float s = 0.f;
#pragma unroll
    for (int i = 0; i < 16; ++i) s += expf(v[i] / ttv - xm);
    __syncthreads();
    float sm = wsum(s);
    if (!lane) red[w] = sm;
    __syncthreads();
    if (t == 0) {
        xmax[bp] = xm;
        Zr[bp] = red[0] + red[1] + red[2] + red[3];
    }
}

__global__ void kzero(int* cnt) {
    int i = blockIdx.x * 256 + threadIdx.x;
    if (i < BB * PP) cnt[i] = 0;
}

// ---- per-(b,n): argmax_p weight, store idx & selected weight -------------
__global__ __launch_bounds__(256) void kargmax(const float* __restrict__ sim,
                                               const float* __restrict__ tt,
                                               const float* __restrict__ xmax,
                                               const float* __restrict__ Zr,
                                               float* __restrict__ wsel,
                                               int* __restrict__ idxv,
                                               int* __restrict__ cnt) {
    int gi = blockIdx.x * 256 + threadIdx.x;
    int b = gi >> 12;
    int n = gi & (NN - 1);
    const float* sp = sim + (size_t)b * PP * NN + n;
    float best = -1.0f;
    int bi = 0;
    for (int p = 0; p < PP; ++p) {
        float s = sp[(size_t)p * NN];
        float w = expf(s / tt[b * PP + p] - xmax[b * PP + p]) / Zr[b * PP + p];
        if (w > best) { best = w; bi = p; }
    }
    idxv[gi] = bi;
    wsel[gi] = best;
    atomicAdd(&cnt[b * PP + bi], 1);
}

// ---- exclusive prefix over p per b ---------------------------------------
__global__ void koffsets(const int* __restrict__ cnt, int* __restrict__ offs) {
    int b = threadIdx.x;
    if (b >= BB) return;
    int s = 0;
    for (int p = 0; p < PP; ++p) {
        offs[b * PP + p] = s;
        s += cnt[b * PP + p];
    }
}

// ---- deterministic sorted lists: packed (p<<12|n) + sorted weights -------
__global__ void klist(const int* __restrict__ idxv, const float* __restrict__ wselp,
                      const int* __restrict__ offs, int* __restrict__ sortn,
                      float* __restrict__ sortw) {
    int g = blockIdx.x * blockDim.x + threadIdx.x;
    int wid = g >> 6, lane = g & 63;
    if (wid >= BB * PP) return;
    int b = wid >> 5, p = wid & 31;
    const int* ib = idxv + b * NN;
    const float* wb = wselp + b * NN;
    int base = offs[wid];
    for (int s = 0; s < NN; s += 64) {
        int v = ib[s + lane];
        float wv = wb[s + lane];
        bool m = (v == p);
        unsigned long long bal = __ballot(m);
        if (m) {
            int rank = __popcll(bal & ((1ull << lane) - 1ull));
            sortn[b * NN + base + rank] = (p << 12) | (s + lane);
            sortw[b * NN + base + rank] = wv;
        }
        base += __popcll(bal);
    }
}

// ---- update: window of 128 sorted rows, float4 streaming gather ----------
// grid: BB*NWIN blocks, 192 threads. Thread t owns d-cols [4t,4t+4).
__global__ __launch_bounds__(192) void kupdate(const float* __restrict__ feats,
                                               const int* __restrict__ sortn,
                                               const float* __restrict__ sortw,
                                               float* __restrict__ part) {
    __shared__ int sn[WROWS];
    __shared__ float sw[WROWS];
    int win = blockIdx.x & (NWIN - 1);
    int b = blockIdx.x >> 5;
    int t = threadIdx.x;
    if (t < WROWS) {
        sn[t] = sortn[b * NN + win * WROWS + t];
        sw[t] = sortw[b * NN + win * WROWS + t];
    }
    __syncthreads();
    const float4* fb = (const float4*)(feats + (size_t)b * NN * DD);
    float4* pw = (float4*)(part + (size_t)(b * NWIN + win) * PP * DD);
    float ax = 0.f, ay = 0.f, az = 0.f, aw = 0.f;
    int curp = sn[0] >> 12;
#pragma unroll 8
    for (int j = 0; j < WROWS; ++j) {
        int e = sn[j];
        int p = e >> 12;
        int n = e & 0xFFF;
        float wv = sw[j];
        float4 f = fb[(size_t)n * 192 + t];
        if (p != curp) {  // block-uniform branch, rare (sorted)
            float4 o = {ax, ay, az, aw};
            pw[(size_t)curp * 192 + t] = o;
            ax = ay = az = aw = 0.f;
            curp = p;
        }
        ax = fmaf(wv, f.x, ax);
        ay = fmaf(wv, f.y, ay);
        az = fmaf(wv, f.z, az);
        aw = fmaf(wv, f.w, aw);
    }
    float4 o = {ax, ay, az, aw};
    pw[(size_t)curp * 192 + t] = o;
}

// ---- reduce window partials -> prototypes (+norms, + final out) ----------
__global__ __launch_bounds__(192) void kreduce(const float* __restrict__ part,
                                               const int* __restrict__ offs,
                                               const int* __restrict__ cnt,
                                               float* __restrict__ prot,
                                               float* __restrict__ npn,
                                               float* __restrict__ outp) {
    int bp = blockIdx.x;
    int b = bp >> 5, p = bp & 31;
    int t = threadIdx.x;
    __shared__ float red[3];
    float4 s = {0.f, 0.f, 0.f, 0.f};
    int c = cnt[bp];
    if (c > 0) {
        int j0 = offs[bp];
        int w0 = j0 >> 7, w1 = (j0 + c - 1) >> 7;
        const float4* pr = (const float4*)(part);
        for (int w = w0; w <= w1; ++w) {
            float4 v = pr[(size_t)((b * NWIN + w) * PP + p) * 192 + t];
            s.x += v.x; s.y += v.y; s.z += v.z; s.w += v.w;
        }
    }
    ((float4*)(prot + (size_t)bp * DD))[t] = s;
    if (outp) ((float4*)(outp + (size_t)bp * DD))[t] = s;
    float sq = s.x * s.x + s.y * s.y + s.z * s.z + s.w * s.w;
    float m = wsum(sq);
    int lane = t & 63, w = t >> 6;
    if (!lane) red[w] = m;
    __syncthreads();
    if (t == 0) npn[bp] = sqrtf(red[0] + red[1] + red[2]);
}

extern "C" void kernel_launch(void* const* d_in, const int* in_sizes, int n_in,
                              void* d_out, int out_size, void* d_ws, size_t ws_size,
                              hipStream_t stream) {
    const float* protIn = (const float*)d_in[0];
    const float* feats = (const float*)d_in[1];
    const float* forg = (const float*)d_in[2];
    float* out = (float*)d_out;

    char* w = (char*)d_ws;
    auto alloc = [&](size_t bytes) {
        char* p = w;
        w += (bytes + 255) & ~(size_t)255;
        return p;
    };
    float* sim = (float*)alloc((size_t)BB * PP * NN * 4);
    float* prot = (float*)alloc((size_t)BB * PP * DD * 4);
    float* part = (float*)alloc((size_t)BB * NWIN * PP * DD * 4);
    float* nfn = (float*)alloc((size_t)BB * NN * 4);
    float* norg = (float*)alloc((size_t)MM * 4);
    float* npn = (float*)alloc(BB * PP * 4);
    float* xmax = (float*)alloc(BB * PP * 4);
    float* Zr = (float*)alloc(BB * PP * 4);
    float* tt = (float*)alloc(BB * PP * 4);
    float* wselp = (float*)alloc((size_t)BB * NN * 4);
    int* idx = (int*)alloc((size_t)BB * NN * 4);
    int* sortn = (int*)alloc((size_t)BB * NN * 4);
    float* sortw = (float*)alloc((size_t)BB * NN * 4);
    int* cnt = (int*)alloc(BB * PP * 4);
    int* offs = (int*)alloc(BB * PP * 4);

    kinit<<<4, 256, 0, stream>>>(tt);
    kprotcopy<<<BB * PP, 256, 0, stream>>>(protIn, prot, npn);
    knorm_rows<<<(BB * NN) / 4, 256, 0, stream>>>(feats, nfn, BB * NN);
    knorm_rows<<<MM / 4, 256, 0, stream>>>(forg, norg, MM);

    for (int t = 0; t < 5; ++t) {
        ksim<<<BB * (NN / NT), 256, 0, stream>>>(prot, feats, nfn, npn, sim, NN / NT,
                                                 (size_t)NN * DD, NN, NN);
        if (t > 0) kdens<<<(BB * PP) / 4, 256, 0, stream>>>(sim, sortn, offs, cnt, tt);
        krowstats<<<BB * PP, 256, 0, stream>>>(sim, tt, xmax, Zr);
        kzero<<<4, 256, 0, stream>>>(cnt);
        kargmax<<<(BB * NN) / 256, 256, 0, stream>>>(sim, tt, xmax, Zr, wselp, idx, cnt);
        koffsets<<<1, 64, 0, stream>>>(cnt, offs);
        klist<<<(BB * PP) / 4, 256, 0, stream>>>(idx, wselp, offs, sortn, sortw);
        kupdate<<<BB * NWIN, 192, 0, stream>>>(feats, sortn, sortw, part);
        kreduce<<<BB * PP, 192, 0, stream>>>(part, offs, cnt, prot, npn,
                                             (t == 4) ? out : nullptr);
    }
    // final similarity against feats_org -> second output region
    ksim<<<BB * (MM / NT), 256, 0, stream>>>(prot, forg, norg, npn,
                                             out + (size_t)BB * PP * DD, MM / NT,
                                             (size_t)0, 0, MM);
}

// Round 4
// 1733.755 us; speedup vs baseline: 1.7631x; 1.0014x over previous
//
#include <hip/hip_runtime.h>
#include <math.h>

#define BB 32
#define PP 32
#define NN 4096
#define DD 768
#define MM 4096
#define WROWS 64           // rows per update window
#define NWIN (NN / WROWS)  // 64 windows per b
#define NT 256             // n-tile in sim gemm
#define KC 32              // k-chunk in sim gemm

__device__ __forceinline__ float wsum(float v) {
    for (int o = 32; o > 0; o >>= 1) v += __shfl_down(v, o, 64);
    return v;
}
__device__ __forceinline__ float wmax(float v) {
    for (int o = 32; o > 0; o >>= 1) v = fmaxf(v, __shfl_down(v, o, 64));
    return v;
}

// ---- tt = TEMP*TAU0 init -------------------------------------------------
__global__ void kinit(float* tt) {
    int i = blockIdx.x * 256 + threadIdx.x;
    if (i < BB * PP) tt[i] = 0.1f * 0.1f;
}

// ---- row L2 norms (feats rows / feats_org rows) --------------------------
__global__ void knorm_rows(const float* __restrict__ x, float* __restrict__ nrm, int rows) {
    int g = blockIdx.x * blockDim.x + threadIdx.x;
    int wid = g >> 6, lane = g & 63;
    if (wid >= rows) return;
    const float4* r = (const float4*)(x + (size_t)wid * DD);
    float s = 0.f;
#pragma unroll
    for (int q = 0; q < 3; ++q) {
        float4 v = r[lane + 64 * q];
        s += v.x * v.x + v.y * v.y + v.z * v.z + v.w * v.w;
    }
    s = wsum(s);
    if (lane == 0) nrm[wid] = sqrtf(s);
}

// ---- copy input prototypes to ws + norms ---------------------------------
__global__ __launch_bounds__(256) void kprotcopy(const float* __restrict__ src,
                                                 float* __restrict__ prot,
                                                 float* __restrict__ npn) {
    int bp = blockIdx.x;
    int t = threadIdx.x;
    __shared__ float red[4];
    const float* s = src + (size_t)bp * DD;
    float* d = prot + (size_t)bp * DD;
    float sq = 0.f;
#pragma unroll
    for (int r = 0; r < 3; ++r) {
        float v = s[t + 256 * r];
        d[t + 256 * r] = v;
        sq += v * v;
    }
    float m = wsum(sq);
    int lane = t & 63, w = t >> 6;
    if (!lane) red[w] = m;
    __syncthreads();
    if (t == 0) npn[bp] = sqrtf(red[0] + red[1] + red[2] + red[3]);
}

// ---- cosine-similarity GEMM:  out[b,p,n] = dot/max(npn*nfn,eps) ----------
// 256-wide n tile, 256 threads, each computes 4p x 8n.
__global__ __launch_bounds__(256) void ksim(
    const float* __restrict__ prot, const float* __restrict__ feats,
    const float* __restrict__ nfn, const float* __restrict__ npn,
    float* __restrict__ out, int ntiles, size_t fsb, int nsb, int Nout) {
    __shared__ float fsT[KC][NT + 2];  // [32][258] transposed feats tile
    __shared__ float psT[KC][PP + 4];  // [32][36]  transposed prot tile
    int bid = blockIdx.x;
    int b = bid / ntiles, nt = bid - b * ntiles;
    int n0 = nt * NT;
    const float4* f4 = (const float4*)(feats + (size_t)b * fsb + (size_t)n0 * DD);
    const float4* p4 = (const float4*)(prot + (size_t)b * (PP * DD));
    int tid = threadIdx.x;
    int tn = tid & 31, tp = tid >> 5;
    float acc[4][8] = {};
    float4 fA[8], pA;
#pragma unroll
    for (int q = 0; q < 8; ++q) {
        int i = q * 256 + tid;
        fA[q] = f4[(size_t)(i >> 3) * 192 + (i & 7)];
    }
    pA = p4[(size_t)(tid >> 3) * 192 + (tid & 7)];
    for (int kc = 0; kc < DD / KC; ++kc) {
        __syncthreads();
#pragma unroll
        for (int q = 0; q < 8; ++q) {
            int i = q * 256 + tid;
            int n_ = i >> 3, g = (i & 7) * 4;
            fsT[g + 0][n_] = fA[q].x;
            fsT[g + 1][n_] = fA[q].y;
            fsT[g + 2][n_] = fA[q].z;
            fsT[g + 3][n_] = fA[q].w;
        }
        {
            int p_ = tid >> 3, g = (tid & 7) * 4;
            psT[g + 0][p_] = pA.x;
            psT[g + 1][p_] = pA.y;
            psT[g + 2][p_] = pA.z;
            psT[g + 3][p_] = pA.w;
        }
        __syncthreads();
        if (kc + 1 < DD / KC) {
            int k8 = (kc + 1) * 8;
#pragma unroll
            for (int q = 0; q < 8; ++q) {
                int i = q * 256 + tid;
                fA[q] = f4[(size_t)(i >> 3) * 192 + k8 + (i & 7)];
            }
            pA = p4[(size_t)(tid >> 3) * 192 + k8 + (tid & 7)];
        }
#pragma unroll
        for (int k = 0; k < KC; ++k) {
            float2 na0 = *(const float2*)&fsT[k][2 * tn];
            float2 na1 = *(const float2*)&fsT[k][2 * tn + 64];
            float2 na2 = *(const float2*)&fsT[k][2 * tn + 128];
            float2 na3 = *(const float2*)&fsT[k][2 * tn + 192];
            float4 pv = *(const float4*)&psT[k][4 * tp];
            float nav[8] = {na0.x, na0.y, na1.x, na1.y, na2.x, na2.y, na3.x, na3.y};
            float pvv[4] = {pv.x, pv.y, pv.z, pv.w};
#pragma unroll
            for (int i = 0; i < 4; ++i)
#pragma unroll
                for (int j = 0; j < 8; ++j)
                    acc[i][j] = fmaf(pvv[i], nav[j], acc[i][j]);
        }
    }
    float2 nf[4];
#pragma unroll
    for (int q = 0; q < 4; ++q)
        nf[q] = *(const float2*)&nfn[(size_t)b * nsb + n0 + 2 * tn + 64 * q];
#pragma unroll
    for (int i = 0; i < 4; ++i) {
        int p = 4 * tp + i;
        float pn = npn[b * PP + p];
        float* ob = out + (size_t)(b * PP + p) * Nout + n0;
#pragma unroll
        for (int q = 0; q < 4; ++q) {
            float2 o;
            o.x = acc[i][2 * q] / fmaxf(pn * nf[q].x, 1e-8f);
            o.y = acc[i][2 * q + 1] / fmaxf(pn * nf[q].y, 1e-8f);
            *(float2*)&ob[2 * tn + 64 * q] = o;
        }
    }
}

// ---- density -> tau (prev iter's sorted buckets, this iter's sim) --------
__global__ void kdens(const float* __restrict__ sim, const int* __restrict__ sortn,
                      const int* __restrict__ offs, const int* __restrict__ cnt,
                      float* __restrict__ tt) {
    int g = blockIdx.x * blockDim.x + threadIdx.x;
    int wid = g >> 6, lane = g & 63;
    if (wid >= BB * PP) return;
    int b = wid >> 5;
    int c = cnt[wid];
    const float* sp = sim + (size_t)wid * NN;
    const int* lp = sortn + b * NN + offs[wid];
    float s = 0.f;
    for (int j = lane; j < c; j += 64) s += sp[lp[j] & 0xFFF];
    s = wsum(s);
    if (lane == 0) {
        float density = 1.0f;
        if (c >= 1) density = 1.0f - s / (float)c;
        float tau = fmaxf(density, 1e-10f);
        tt[wid] = 0.1f * tau;
    }
}

// ---- per-row softmax stats: xmax = max(sim)/tt, Z = sum exp(x - xmax) ----
__global__ __launch_bounds__(256) void krowstats(const float* __restrict__ sim,
                                                 const float* __restrict__ tt,
                                                 float* __restrict__ xmax,
                                                 float* __restrict__ Zr) {
    int bp = blockIdx.x;
    int t = threadIdx.x;
    const float4* r4 = (const float4*)(sim + (size_t)bp * NN);
    float v[16];
    float mx = -3.4e38f;
#pragma unroll
    for (int q = 0; q < 4; ++q) {
        float4 x = r4[t + 256 * q];
        v[4 * q + 0] = x.x; v[4 * q + 1] = x.y; v[4 * q + 2] = x.z; v[4 * q + 3] = x.w;
        mx = fmaxf(mx, fmaxf(fmaxf(x.x, x.y), fmaxf(x.z, x.w)));
    }
    __shared__ float red[4];
    float m = wmax(mx);
    int lane = t & 63, w = t >> 6;
    if (!lane) red[w] = m;
    __syncthreads();
    float bm = fmaxf(fmaxf(red[0], red[1]), fmaxf(red[2], red[3]));
    float ttv = tt[bp];
    float xm = bm / ttv;
    float s = 0.f;
#pragma unroll
    for (int i = 0; i < 16; ++i) s += expf(v[i] / ttv - xm);
    __syncthreads();
    float sm = wsum(s);
    if (!lane) red[w] = sm;
    __syncthreads();
    if (t == 0) {
        xmax[bp] = xm;
        Zr[bp] = red[0] + red[1] + red[2] + red[3];
    }
}

__global__ void kzero(int* cnt) {
    int i = blockIdx.x * 256 + threadIdx.x;
    if (i < BB * PP) cnt[i] = 0;
}

// ---- per-(b,n): argmax_p weight, store idx & selected weight -------------
__global__ __launch_bounds__(256) void kargmax(const float* __restrict__ sim,
                                               const float* __restrict__ tt,
                                               const float* __restrict__ xmax,
                                               const float* __restrict__ Zr,
                                               float* __restrict__ wsel,
                                               int* __restrict__ idxv,
                                               int* __restrict__ cnt) {
    int gi = blockIdx.x * 256 + threadIdx.x;
    int b = gi >> 12;
    int n = gi & (NN - 1);
    const float* sp = sim + (size_t)b * PP * NN + n;
    float best = -1.0f;
    int bi = 0;
    for (int p = 0; p < PP; ++p) {
        float s = sp[(size_t)p * NN];
        float w = expf(s / tt[b * PP + p] - xmax[b * PP + p]) / Zr[b * PP + p];
        if (w > best) { best = w; bi = p; }
    }
    idxv[gi] = bi;
    wsel[gi] = best;
    atomicAdd(&cnt[b * PP + bi], 1);
}

// ---- exclusive prefix over p per b ---------------------------------------
__global__ void koffsets(const int* __restrict__ cnt, int* __restrict__ offs) {
    int b = threadIdx.x;
    if (b >= BB) return;
    int s = 0;
    for (int p = 0; p < PP; ++p) {
        offs[b * PP + p] = s;
        s += cnt[b * PP + p];
    }
}

// ---- deterministic sorted lists: packed (p<<12|n) + sorted weights -------
__global__ void klist(const int* __restrict__ idxv, const float* __restrict__ wselp,
                      const int* __restrict__ offs, int* __restrict__ sortn,
                      float* __restrict__ sortw) {
    int g = blockIdx.x * blockDim.x + threadIdx.x;
    int wid = g >> 6, lane = g & 63;
    if (wid >= BB * PP) return;
    int b = wid >> 5, p = wid & 31;
    const int* ib = idxv + b * NN;
    const float* wb = wselp + b * NN;
    int base = offs[wid];
    for (int s = 0; s < NN; s += 64) {
        int v = ib[s + lane];
        float wv = wb[s + lane];
        bool m = (v == p);
        unsigned long long bal = __ballot(m);
        if (m) {
            int rank = __popcll(bal & ((1ull << lane) - 1ull));
            sortn[b * NN + base + rank] = (p << 12) | (s + lane);
            sortw[b * NN + base + rank] = wv;
        }
        base += __popcll(bal);
    }
}

// ---- update: window of 64 sorted rows, float4 streaming gather -----------
// grid: BB*NWIN blocks, 192 threads. Thread t owns d-cols [4t,4t+4).
__global__ __launch_bounds__(192) void kupdate(const float* __restrict__ feats,
                                               const int* __restrict__ sortn,
                                               const float* __restrict__ sortw,
                                               float* __restrict__ part) {
    __shared__ int sn[WROWS];
    __shared__ float sw[WROWS];
    int win = blockIdx.x & (NWIN - 1);
    int b = blockIdx.x >> 6;
    int t = threadIdx.x;
    if (t < WROWS) {
        sn[t] = sortn[b * NN + win * WROWS + t];
        sw[t] = sortw[b * NN + win * WROWS + t];
    }
    __syncthreads();
    const float4* fb = (const float4*)(feats + (size_t)b * NN * DD);
    float4* pw = (float4*)(part + (size_t)(b * NWIN + win) * PP * DD);
    float ax = 0.f, ay = 0.f, az = 0.f, aw = 0.f;
    int curp = sn[0] >> 12;
#pragma unroll 8
    for (int j = 0; j < WROWS; ++j) {
        int e = sn[j];
        int p = e >> 12;
        int n = e & 0xFFF;
        float wv = sw[j];
        float4 f = fb[(size_t)n * 192 + t];
        if (p != curp) {  // block-uniform branch, rare (sorted)
            float4 o = {ax, ay, az, aw};
            pw[(size_t)curp * 192 + t] = o;
            ax = ay = az = aw = 0.f;
            curp = p;
        }
        ax = fmaf(wv, f.x, ax);
        ay = fmaf(wv, f.y, ay);
        az = fmaf(wv, f.z, az);
        aw = fmaf(wv, f.w, aw);
    }
    float4 o = {ax, ay, az, aw};
    pw[(size_t)curp * 192 + t] = o;
}

// ---- reduce window partials -> prototypes (+norms, + final out) ----------
__global__ __launch_bounds__(192) void kreduce(const float* __restrict__ part,
                                               const int* __restrict__ offs,
                                               const int* __restrict__ cnt,
                                               float* __restrict__ prot,
                                               float* __restrict__ npn,
                                               float* __restrict__ outp) {
    int bp = blockIdx.x;
    int b = bp >> 5, p = bp & 31;
    int t = threadIdx.x;
    __shared__ float red[3];
    float4 s = {0.f, 0.f, 0.f, 0.f};
    int c = cnt[bp];
    if (c > 0) {
        int j0 = offs[bp];
        int w0 = j0 >> 6, w1 = (j0 + c - 1) >> 6;
        const float4* pr = (const float4*)(part);
        for (int w = w0; w <= w1; ++w) {
            float4 v = pr[(size_t)((b * NWIN + w) * PP + p) * 192 + t];
            s.x += v.x; s.y += v.y; s.z += v.z; s.w += v.w;
        }
    }
    ((float4*)(prot + (size_t)bp * DD))[t] = s;
    if (outp) ((float4*)(outp + (size_t)bp * DD))[t] = s;
    float sq = s.x * s.x + s.y * s.y + s.z * s.z + s.w * s.w;
    float m = wsum(sq);
    int lane = t & 63, w = t >> 6;
    if (!lane) red[w] = m;
    __syncthreads();
    if (t == 0) npn[bp] = sqrtf(red[0] + red[1] + red[2]);
}

extern "C" void kernel_launch(void* const* d_in, const int* in_sizes, int n_in,
                              void* d_out, int out_size, void* d_ws, size_t ws_size,
                              hipStream_t stream) {
    const float* protIn = (const float*)d_in[0];
    const float* feats = (const float*)d_in[1];
    const float* forg = (const float*)d_in[2];
    float* out = (float*)d_out;

    char* w = (char*)d_ws;
    auto alloc = [&](size_t bytes) {
        char* p = w;
        w += (bytes + 255) & ~(size_t)255;
        return p;
    };
    float* sim = (float*)alloc((size_t)BB * PP * NN * 4);
    float* prot = (float*)alloc((size_t)BB * PP * DD * 4);
    float* part = (float*)alloc((size_t)BB * NWIN * PP * DD * 4);
    float* nfn = (float*)alloc((size_t)BB * NN * 4);
    float* norg = (float*)alloc((size_t)MM * 4);
    float* npn = (float*)alloc(BB * PP * 4);
    float* xmax = (float*)alloc(BB * PP * 4);
    float* Zr = (float*)alloc(BB * PP * 4);
    float* tt = (float*)alloc(BB * PP * 4);
    float* wselp = (float*)alloc((size_t)BB * NN * 4);
    int* idx = (int*)alloc((size_t)BB * NN * 4);
    int* sortn = (int*)alloc((size_t)BB * NN * 4);
    float* sortw = (float*)alloc((size_t)BB * NN * 4);
    int* cnt = (int*)alloc(BB * PP * 4);
    int* offs = (int*)alloc(BB * PP * 4);

    kinit<<<4, 256, 0, stream>>>(tt);
    kprotcopy<<<BB * PP, 256, 0, stream>>>(protIn, prot, npn);
    knorm_rows<<<(BB * NN) / 4, 256, 0, stream>>>(feats, nfn, BB * NN);
    knorm_rows<<<MM / 4, 256, 0, stream>>>(forg, norg, MM);

    for (int t = 0; t < 5; ++t) {
        ksim<<<BB * (NN / NT), 256, 0, stream>>>(prot, feats, nfn, npn, sim, NN / NT,
                                                 (size_t)NN * DD, NN, NN);
        if (t > 0) kdens<<<(BB * PP) / 4, 256, 0, stream>>>(sim, sortn, offs, cnt, tt);
        krowstats<<<BB * PP, 256, 0, stream>>>(sim, tt, xmax, Zr);
        kzero<<<4, 256, 0, stream>>>(cnt);
        kargmax<<<(BB * NN) / 256, 256, 0, stream>>>(sim, tt, xmax, Zr, wselp, idx, cnt);
        koffsets<<<1, 64, 0, stream>>>(cnt, offs);
        klist<<<(BB * PP) / 4, 256, 0, stream>>>(idx, wselp, offs, sortn, sortw);
        kupdate<<<BB * NWIN, 192, 0, stream>>>(feats, sortn, sortw, part);
        kreduce<<<BB * PP, 192, 0, stream>>>(part, offs, cnt, prot, npn,
                                             (t == 4) ? out : nullptr);
    }
    // final similarity against feats_org -> second output region
    ksim<<<BB * (MM / NT), 256, 0, stream>>>(prot, forg, norg, npn,
                                             out + (size_t)BB * PP * DD, MM / NT,
                                             (size_t)0, 0, MM);
}